// Round 12
// baseline (35.315 us; speedup 1.0000x reference)
//
#include <hip/hip_runtime.h>
#include <math.h>

typedef _Float16 h2 __attribute__((ext_vector_type(2)));
typedef _Float16 h4 __attribute__((ext_vector_type(4)));

#define PD 68                  // 64 + 2*2 halo
#define PD2 (PD * PD)          // 4624
#define PVOL (PD * PD * PD)    // 314432
#define NBLK2 1024

// arg = -theta^2/sigma_th^2 = KE * u * h(u), u = 1 - dot
// KE = -2 / radians(20)^2
#define KE (-16.4140429822f)

// 2-way fp16 dot with f32 accumulate (v_dot2_f32_f16); cvt fallback.
__device__ __forceinline__ float hdot(h2 a, h2 b, float c) {
#if __has_builtin(__builtin_amdgcn_fdot2)
    return __builtin_amdgcn_fdot2(a, b, c, false);
#else
    return fmaf((float)a.x, (float)b.x, fmaf((float)a.y, (float)b.y, c));
#endif
}

// ---------------- pass 1: normalize + mask-fold + zero-pad (fp16) ------------
// q stores n_hat * mask as half4 (8 B/voxel, w=0). Masked or out-of-volume
// voxels are the zero vector; |q|^2 (via fdot2) recovers the mask.

__global__ __launch_bounds__(256) void pad_normalize_kernel(
    const float* __restrict__ n_pred,   // (2,3,64,64,64)
    const float* __restrict__ src,      // (2,1,64,64,64)
    h4* __restrict__ q)                 // (2,68,68,68) padded
{
    int idx = blockIdx.x * 256 + threadIdx.x;
    if (idx >= 2 * PVOL) return;
    int b = idx / PVOL;
    int r = idx - b * PVOL;
    int z = r / PD2;
    int r2 = r - z * PD2;
    int y = r2 / PD;
    int x = r2 - y * PD;
    int gx = x - 2, gy = y - 2, gz = z - 2;
    float vx = 0.f, vy = 0.f, vz = 0.f;
    if ((unsigned)gx < 64u && (unsigned)gy < 64u && (unsigned)gz < 64u) {
        const size_t cs = 262144;  // 64^3
        size_t vox = ((size_t)gz * 64 + gy) * 64 + gx;
        size_t off = (size_t)b * 3 * cs + vox;
        float xx = n_pred[off];
        float yy = n_pred[off + cs];
        float zz = n_pred[off + 2 * cs];
        float inv = 1.0f / fmaxf(sqrtf(xx * xx + yy * yy + zz * zz), 1e-6f);
        // sigmoid(s) > 0.5 <=> s > 0 ; fold mask into the vector
        if (src[(size_t)b * cs + vox] > 0.0f) {
            vx = xx * inv; vy = yy * inv; vz = zz * inv;
        }
    }
    h4 h;
    h.x = (_Float16)vx; h.y = (_Float16)vy; h.z = (_Float16)vz;
    h.w = (_Float16)0.f;
    q[idx] = h;
}

// ---------------- pass 2: half-stencil, ZT=2 z-column reuse, fp16 taps -------
// CODEGEN RULE (r5-r10 evidence): keep this exact shape — __expf, one
// mask-skip if around unconditional unrolled loads, plain partials STORE
// epilogue. Any atomic/threadfence/finalize here rolls the load batch.
//
// Each thread owns 2 centers along z. Tap plane z0+k serves c0 as dz=k and
// c1 as dz=k-1: 87 loads serve 124 taps. Positive-half stencil: w symmetric
// => total & count are exactly half the full sums; ratio unchanged.
// Per-center sums are scaled by nn_c at the end (exact gating of masked
// centers; nn_nb gates masked neighbors inside the loop).

__global__ __launch_bounds__(256) void stencil_col2_kernel(
    const h4* __restrict__ q, float2* __restrict__ partials)
{
    int x = threadIdx.x & 63;
    int y = blockIdx.x * 4 + (threadIdx.x >> 6);
    int z0 = blockIdx.y * 2;
    int b = blockIdx.z;
    const h4* base =
        q + (size_t)b * PVOL + ((size_t)(z0 + 2) * PD + (y + 2)) * PD + (x + 2);

    h4 c0v = base[0];
    h4 c1v = base[PD2];
    h2 c0lo = {c0v.x, c0v.y}, c0hi = {c0v.z, c0v.w};
    h2 c1lo = {c1v.x, c1v.y}, c1hi = {c1v.z, c1v.w};
    float nnc0 = hdot(c0lo, c0lo, hdot(c0hi, c0hi, 0.f));
    float nnc1 = hdot(c1lo, c1lo, hdot(c1hi, c1hi, 0.f));

    float tot0 = 0.f, cf0 = 0.f, tot1 = 0.f, cf1 = 0.f;

    auto app = [&](h2 clo, h2 chi, h2 lo, h2 hi, float nn, float coff,
                   float& tt, float& cc) {
        float dot = hdot(clo, lo, hdot(chi, hi, 0.f));
        float u = 1.0f - dot;
        // theta^2 = 2*u*P(u)^2, asin series, deg 4 (bias < 3e-6 rel)
        float p = fmaf(u, 1.8990885e-3f, 5.5803571e-3f);
        p = fmaf(u, p, 1.8750000e-2f);
        p = fmaf(u, p, 8.3333333e-2f);
        p = fmaf(u, p, 1.0f);
        float uh = u * p * p;
        float w = __expf(fmaf(KE, uh, coff));   // w_dist * w_theta
        tt = fmaf(w, nn, tt);                   // nn gates masked neighbor
        cc += nn;
    };

    if (nnc0 + nnc1 > 0.5f) {
        // k = 0 plane: dz=0 half-plane taps for c0 only (12 loads).
#pragma unroll
        for (int dy = -2; dy <= 2; ++dy) {
#pragma unroll
            for (int dx = -2; dx <= 2; ++dx) {
                if (dy > 0 || (dy == 0 && dx > 0)) {
                    h4 v = base[dy * PD + dx];
                    h2 lo = {v.x, v.y}, hi = {v.z, v.w};
                    float nn = hdot(lo, lo, hdot(hi, hi, 0.f));
                    app(c0lo, c0hi, lo, hi, nn,
                        -0.5625f * (float)(dy * dy + dx * dx), tot0, cf0);
                }
            }
        }
        // k = 1..3 planes: 25 loads each, serving c0 (dz=k) and c1 (dz=k-1).
#pragma unroll
        for (int k = 1; k <= 3; ++k) {
#pragma unroll
            for (int dy = -2; dy <= 2; ++dy) {
#pragma unroll
                for (int dx = -2; dx <= 2; ++dx) {
                    h4 v = base[k * PD2 + dy * PD + dx];
                    h2 lo = {v.x, v.y}, hi = {v.z, v.w};
                    float nn = hdot(lo, lo, hdot(hi, hi, 0.f));
                    const int d2 = dy * dy + dx * dx;
                    if (k <= 2)  // dz=k role for c0
                        app(c0lo, c0hi, lo, hi, nn,
                            -0.5625f * (float)(k * k + d2), tot0, cf0);
                    const int dz1 = k - 1;  // role for c1
                    if (dz1 == 0) {
                        if (dy > 0 || (dy == 0 && dx > 0))
                            app(c1lo, c1hi, lo, hi, nn,
                                -0.5625f * (float)d2, tot1, cf1);
                    } else {
                        app(c1lo, c1hi, lo, hi, nn,
                            -0.5625f * (float)(dz1 * dz1 + d2), tot1, cf1);
                    }
                }
            }
        }
    }

    // scale per-center sums by center mask (exact gating), then reduce.
    float tot = fmaf(tot0, nnc0, tot1 * nnc1);
    float cf  = fmaf(cf0,  nnc0, cf1  * nnc1);

#pragma unroll
    for (int s = 32; s > 0; s >>= 1) {
        tot += __shfl_down(tot, s, 64);
        cf  += __shfl_down(cf, s, 64);
    }
    __shared__ float sd[4], sc[4];
    int wid = threadIdx.x >> 6, lane = threadIdx.x & 63;
    if (lane == 0) { sd[wid] = tot; sc[wid] = cf; }
    __syncthreads();
    if (threadIdx.x == 0) {
        int bid = ((int)blockIdx.z * gridDim.y + blockIdx.y) * gridDim.x
                  + blockIdx.x;
        partials[bid] = make_float2(sd[0] + sd[1] + sd[2] + sd[3],
                                    sc[0] + sc[1] + sc[2] + sc[3]);
    }
}

__global__ __launch_bounds__(256) void reduce_kernel(
    const float2* __restrict__ partials, float* __restrict__ out)
{
    double t = 0.0, c = 0.0;
    for (int i = threadIdx.x; i < NBLK2; i += 256) {
        float2 p = partials[i];
        t += (double)p.x;
        c += (double)p.y;
    }
#pragma unroll
    for (int s = 32; s > 0; s >>= 1) {
        t += __shfl_down(t, s, 64);
        c += __shfl_down(c, s, 64);
    }
    __shared__ double sd[4], sc[4];
    int wid = threadIdx.x >> 6, lane = threadIdx.x & 63;
    if (lane == 0) { sd[wid] = t; sc[wid] = c; }
    __syncthreads();
    if (threadIdx.x == 0) {
        double T = sd[0] + sd[1] + sd[2] + sd[3];
        double C = sc[0] + sc[1] + sc[2] + sc[3];
        out[0] = (C == 0.0) ? 0.0f : (float)(T / C);
    }
}

// ---------------- fallback (fused, single kernel) if ws too small ------------

#define TILE 8
#define HALO 2
#define LDIM 12
#define LSZ  1728
#define NVOX 512

__global__ __launch_bounds__(256) void repulsion_fused_kernel(
    const float* __restrict__ n_pred, const float* __restrict__ src,
    double* __restrict__ acc)
{
    __shared__ float4 sn[LSZ];
    __shared__ float rd[4], rc[4];
    const int tx = blockIdx.x * TILE, ty = blockIdx.y * TILE;
    const int b = blockIdx.z >> 3, tz = (blockIdx.z & 7) * TILE;
    const size_t cs = 262144;
    const float* npb = n_pred + (size_t)b * 3 * cs;
    const float* spb = src + (size_t)b * cs;
    for (int i = threadIdx.x; i < LSZ; i += 256) {
        int lx = i % LDIM, t = i / LDIM, ly = t % LDIM, lz = t / LDIM;
        int gx = tx + lx - HALO, gy = ty + ly - HALO, gz = tz + lz - HALO;
        float4 v = make_float4(0.f, 0.f, 0.f, 0.f);
        if ((unsigned)gx < 64u && (unsigned)gy < 64u && (unsigned)gz < 64u) {
            size_t off = ((size_t)gz * 64 + gy) * 64 + gx;
            float xx = npb[off], yy = npb[cs + off], zz = npb[2 * cs + off];
            float inv = 1.0f / fmaxf(sqrtf(xx * xx + yy * yy + zz * zz), 1e-6f);
            float m = (spb[off] > 0.0f) ? 1.0f : 0.0f;
            v = make_float4(xx * inv, yy * inv, zz * inv, m);
        }
        sn[i] = v;
    }
    __syncthreads();
    float tot = 0.0f, cf = 0.0f;
    for (int v = threadIdx.x; v < NVOX; v += 256) {
        int lx = (v & 7) + HALO, ly = ((v >> 3) & 7) + HALO, lz = (v >> 6) + HALO;
        int ci = (lz * LDIM + ly) * LDIM + lx;
        float4 c = sn[ci];
        if (c.w == 0.0f) continue;
#pragma unroll
        for (int dz = -2; dz <= 2; ++dz)
#pragma unroll
            for (int dy = -2; dy <= 2; ++dy)
#pragma unroll
                for (int dx = -2; dx <= 2; ++dx) {
                    if (dz == 0 && dy == 0 && dx == 0) continue;
                    const float coff =
                        -0.5625f * (float)(dz * dz + dy * dy + dx * dx);
                    float4 nb = sn[ci + (dz * LDIM + dy) * LDIM + dx];
                    float dot = fmaf(c.x, nb.x, fmaf(c.y, nb.y, c.z * nb.z));
                    float u = 1.0f - dot;
                    float p = fmaf(u, 1.8990885e-3f, 5.5803571e-3f);
                    p = fmaf(u, p, 1.8750000e-2f);
                    p = fmaf(u, p, 8.3333333e-2f);
                    p = fmaf(u, p, 1.0f);
                    float uh = u * p * p;
                    float w = __expf(fmaf(KE, uh, coff));
                    tot = fmaf(w, nb.w, tot);
                    cf += nb.w;
                }
    }
#pragma unroll
    for (int s = 32; s > 0; s >>= 1) {
        tot += __shfl_down(tot, s, 64);
        cf  += __shfl_down(cf, s, 64);
    }
    int wid = threadIdx.x >> 6, lane = threadIdx.x & 63;
    if (lane == 0) { rd[wid] = tot; rc[wid] = cf; }
    __syncthreads();
    if (threadIdx.x == 0) {
        atomicAdd(&acc[0], (double)rd[0] + rd[1] + rd[2] + rd[3]);
        atomicAdd(&acc[1], (double)rc[0] + rc[1] + rc[2] + rc[3]);
    }
}

__global__ void zero_acc_kernel(double* acc) { acc[0] = 0.0; acc[1] = 0.0; }

__global__ void finalize_kernel(const double* acc, float* out) {
    out[0] = (acc[1] == 0.0) ? 0.0f : (float)(acc[0] / acc[1]);
}

// ---------------- launch -----------------------------------------------------

extern "C" void kernel_launch(void* const* d_in, const int* in_sizes, int n_in,
                              void* d_out, int out_size, void* d_ws, size_t ws_size,
                              hipStream_t stream) {
    const float* n_pred = (const float*)d_in[0];
    const float* src    = (const float*)d_in[1];

    const size_t vol_bytes = (size_t)2 * PVOL * sizeof(h4);  // 5,030,912
    const size_t need = vol_bytes + (size_t)NBLK2 * sizeof(float2);

    if (ws_size >= need) {
        h4* q = (h4*)d_ws;
        float2* partials = (float2*)((char*)d_ws + vol_bytes);
        int nblk = (2 * PVOL + 255) / 256;  // 2457
        pad_normalize_kernel<<<nblk, 256, 0, stream>>>(n_pred, src, q);
        dim3 grid(16, 32, 2);  // (y-tiles of 4, z-tiles of 2, batch) = 1024 blocks
        stencil_col2_kernel<<<grid, 256, 0, stream>>>(q, partials);
        reduce_kernel<<<1, 256, 0, stream>>>(partials, (float*)d_out);
    } else {
        double* acc = (double*)d_ws;
        zero_acc_kernel<<<1, 1, 0, stream>>>(acc);
        dim3 grid(8, 8, 16);
        repulsion_fused_kernel<<<grid, 256, 0, stream>>>(n_pred, src, acc);
        finalize_kernel<<<1, 1, 0, stream>>>(acc, (float*)d_out);
    }
}

// Round 13
// 30.115 us; speedup vs baseline: 1.1727x; 1.1727x over previous
//
#include <hip/hip_runtime.h>
#include <math.h>

#define PD 68                  // 64 + 2*2 halo
#define PD2 (PD * PD)          // 4624
#define PVOL (PD * PD * PD)    // 314432
#define NBLK2 1024

// arg = -theta^2/sigma_th^2 = KE * u * h(u), u = 1 - dot
// KE = -2 / radians(20)^2
#define KE (-16.4140429822f)

// ---------------- pass 1: normalize + zero-pad (verbatim round-4) ------------

__global__ __launch_bounds__(256) void pad_normalize_kernel(
    const float* __restrict__ n_pred,   // (2,3,64,64,64)
    const float* __restrict__ src,      // (2,1,64,64,64)
    float4* __restrict__ q)             // (2,68,68,68) padded
{
    int idx = blockIdx.x * 256 + threadIdx.x;
    if (idx >= 2 * PVOL) return;
    int b = idx / PVOL;
    int r = idx - b * PVOL;
    int z = r / PD2;
    int r2 = r - z * PD2;
    int y = r2 / PD;
    int x = r2 - y * PD;
    int gx = x - 2, gy = y - 2, gz = z - 2;
    float4 v = make_float4(0.f, 0.f, 0.f, 0.f);
    if ((unsigned)gx < 64u && (unsigned)gy < 64u && (unsigned)gz < 64u) {
        const size_t cs = 262144;  // 64^3
        size_t vox = ((size_t)gz * 64 + gy) * 64 + gx;
        size_t off = (size_t)b * 3 * cs + vox;
        float xx = n_pred[off];
        float yy = n_pred[off + cs];
        float zz = n_pred[off + 2 * cs];
        float inv = 1.0f / fmaxf(sqrtf(xx * xx + yy * yy + zz * zz), 1e-6f);
        float m = (src[(size_t)b * cs + vox] > 0.0f) ? 1.0f : 0.0f;  // sig>0.5
        v = make_float4(xx * inv, yy * inv, zz * inv, m);
    }
    q[idx] = v;
}

// ---------------- pass 2: half-stencil, ZT=2 z-column reuse ------------------
// CODEGEN RULE (r5-r10 evidence): this kernel must keep the round-4 shape —
// __expf (not exp2f), unconditional unrolled loads inside one mask-skip if,
// and a plain partials STORE epilogue. Any atomic/threadfence/last-block
// finalize in this function rolls the load batch (VGPR->32, 6x slower).
// NUMERICS RULE (r7/r12 evidence): keep mask in the w channel — encodings
// that recover the mask from |q|^2 add per-tap VALU and net-lose.
//
// Each thread owns 2 centers along z (c0@z0, c1@z0+1). Tap plane z0+k serves
// c0 as dz=k and c1 as dz=k-1: 87 loads serve 124 taps (43.5 loads/voxel vs
// 62). Positive-half stencil: w symmetric => total & count are exactly half
// the full sums; ratio unchanged.

__global__ __launch_bounds__(256) void stencil_col2_kernel(
    const float4* __restrict__ q, float2* __restrict__ partials)
{
    int x = threadIdx.x & 63;
    int y = blockIdx.x * 4 + (threadIdx.x >> 6);
    int z0 = blockIdx.y * 2;
    int b = blockIdx.z;
    const float4* base =
        q + (size_t)b * PVOL + ((size_t)(z0 + 2) * PD + (y + 2)) * PD + (x + 2);

    float4 c0 = base[0];
    float4 c1 = base[PD2];

    float tot = 0.0f, cf = 0.0f;

    auto app = [&](const float4& c, const float4& nb, float coff) {
        float dot = fmaf(c.x, nb.x, fmaf(c.y, nb.y, c.z * nb.z));
        float u = 1.0f - dot;
        // theta^2 = 2*u*P(u)^2, asin series, deg 4 (bias < 3e-6 rel)
        float p = fmaf(u, 1.8990885e-3f, 5.5803571e-3f);
        p = fmaf(u, p, 1.8750000e-2f);
        p = fmaf(u, p, 8.3333333e-2f);
        p = fmaf(u, p, 1.0f);
        float uh = u * p * p;
        float w = __expf(fmaf(KE, uh, coff));   // w_dist * w_theta
        float g = nb.w * c.w;                   // both masks (0/1)
        tot = fmaf(w, g, tot);
        cf += g;
    };

    if (c0.w + c1.w != 0.0f) {
        // k = 0 plane: dz=0 half-plane taps for c0 only (12 loads).
#pragma unroll
        for (int dy = -2; dy <= 2; ++dy) {
#pragma unroll
            for (int dx = -2; dx <= 2; ++dx) {
                if (dy > 0 || (dy == 0 && dx > 0)) {
                    float4 nb = base[dy * PD + dx];
                    app(c0, nb, -0.5625f * (float)(dy * dy + dx * dx));
                }
            }
        }
        // k = 1..3 planes: 25 loads each, serving c0 (dz=k) and c1 (dz=k-1).
#pragma unroll
        for (int k = 1; k <= 3; ++k) {
#pragma unroll
            for (int dy = -2; dy <= 2; ++dy) {
#pragma unroll
                for (int dx = -2; dx <= 2; ++dx) {
                    float4 nb = base[k * PD2 + dy * PD + dx];
                    const int d2 = dy * dy + dx * dx;
                    if (k <= 2)  // dz=k role for c0
                        app(c0, nb, -0.5625f * (float)(k * k + d2));
                    const int dz1 = k - 1;  // role for c1
                    if (dz1 == 0) {
                        if (dy > 0 || (dy == 0 && dx > 0))
                            app(c1, nb, -0.5625f * (float)d2);
                    } else {
                        app(c1, nb, -0.5625f * (float)(dz1 * dz1 + d2));
                    }
                }
            }
        }
    }

    // 64-lane wave reduction + partials STORE (keep this epilogue shape!).
#pragma unroll
    for (int s = 32; s > 0; s >>= 1) {
        tot += __shfl_down(tot, s, 64);
        cf  += __shfl_down(cf, s, 64);
    }
    __shared__ float sd[4], sc[4];
    int wid = threadIdx.x >> 6, lane = threadIdx.x & 63;
    if (lane == 0) { sd[wid] = tot; sc[wid] = cf; }
    __syncthreads();
    if (threadIdx.x == 0) {
        int bid = ((int)blockIdx.z * gridDim.y + blockIdx.y) * gridDim.x
                  + blockIdx.x;
        partials[bid] = make_float2(sd[0] + sd[1] + sd[2] + sd[3],
                                    sc[0] + sc[1] + sc[2] + sc[3]);
    }
}

__global__ __launch_bounds__(256) void reduce_kernel(
    const float2* __restrict__ partials, float* __restrict__ out)
{
    double t = 0.0, c = 0.0;
    for (int i = threadIdx.x; i < NBLK2; i += 256) {
        float2 p = partials[i];
        t += (double)p.x;
        c += (double)p.y;
    }
#pragma unroll
    for (int s = 32; s > 0; s >>= 1) {
        t += __shfl_down(t, s, 64);
        c += __shfl_down(c, s, 64);
    }
    __shared__ double sd[4], sc[4];
    int wid = threadIdx.x >> 6, lane = threadIdx.x & 63;
    if (lane == 0) { sd[wid] = t; sc[wid] = c; }
    __syncthreads();
    if (threadIdx.x == 0) {
        double T = sd[0] + sd[1] + sd[2] + sd[3];
        double C = sc[0] + sc[1] + sc[2] + sc[3];
        out[0] = (C == 0.0) ? 0.0f : (float)(T / C);
    }
}

// ---------------- fallback (fused, single kernel) if ws too small ------------

#define TILE 8
#define HALO 2
#define LDIM 12
#define LSZ  1728
#define NVOX 512

__global__ __launch_bounds__(256) void repulsion_fused_kernel(
    const float* __restrict__ n_pred, const float* __restrict__ src,
    double* __restrict__ acc)
{
    __shared__ float4 sn[LSZ];
    __shared__ float rd[4], rc[4];
    const int tx = blockIdx.x * TILE, ty = blockIdx.y * TILE;
    const int b = blockIdx.z >> 3, tz = (blockIdx.z & 7) * TILE;
    const size_t cs = 262144;
    const float* npb = n_pred + (size_t)b * 3 * cs;
    const float* spb = src + (size_t)b * cs;
    for (int i = threadIdx.x; i < LSZ; i += 256) {
        int lx = i % LDIM, t = i / LDIM, ly = t % LDIM, lz = t / LDIM;
        int gx = tx + lx - HALO, gy = ty + ly - HALO, gz = tz + lz - HALO;
        float4 v = make_float4(0.f, 0.f, 0.f, 0.f);
        if ((unsigned)gx < 64u && (unsigned)gy < 64u && (unsigned)gz < 64u) {
            size_t off = ((size_t)gz * 64 + gy) * 64 + gx;
            float xx = npb[off], yy = npb[cs + off], zz = npb[2 * cs + off];
            float inv = 1.0f / fmaxf(sqrtf(xx * xx + yy * yy + zz * zz), 1e-6f);
            float m = (spb[off] > 0.0f) ? 1.0f : 0.0f;
            v = make_float4(xx * inv, yy * inv, zz * inv, m);
        }
        sn[i] = v;
    }
    __syncthreads();
    float tot = 0.0f, cf = 0.0f;
    for (int v = threadIdx.x; v < NVOX; v += 256) {
        int lx = (v & 7) + HALO, ly = ((v >> 3) & 7) + HALO, lz = (v >> 6) + HALO;
        int ci = (lz * LDIM + ly) * LDIM + lx;
        float4 c = sn[ci];
        if (c.w == 0.0f) continue;
#pragma unroll
        for (int dz = -2; dz <= 2; ++dz)
#pragma unroll
            for (int dy = -2; dy <= 2; ++dy)
#pragma unroll
                for (int dx = -2; dx <= 2; ++dx) {
                    if (dz == 0 && dy == 0 && dx == 0) continue;
                    const float coff =
                        -0.5625f * (float)(dz * dz + dy * dy + dx * dx);
                    float4 nb = sn[ci + (dz * LDIM + dy) * LDIM + dx];
                    float dot = fmaf(c.x, nb.x, fmaf(c.y, nb.y, c.z * nb.z));
                    float u = 1.0f - dot;
                    float p = fmaf(u, 1.8990885e-3f, 5.5803571e-3f);
                    p = fmaf(u, p, 1.8750000e-2f);
                    p = fmaf(u, p, 8.3333333e-2f);
                    p = fmaf(u, p, 1.0f);
                    float uh = u * p * p;
                    float w = __expf(fmaf(KE, uh, coff));
                    tot = fmaf(w, nb.w, tot);
                    cf += nb.w;
                }
    }
#pragma unroll
    for (int s = 32; s > 0; s >>= 1) {
        tot += __shfl_down(tot, s, 64);
        cf  += __shfl_down(cf, s, 64);
    }
    int wid = threadIdx.x >> 6, lane = threadIdx.x & 63;
    if (lane == 0) { rd[wid] = tot; rc[wid] = cf; }
    __syncthreads();
    if (threadIdx.x == 0) {
        atomicAdd(&acc[0], (double)rd[0] + rd[1] + rd[2] + rd[3]);
        atomicAdd(&acc[1], (double)rc[0] + rc[1] + rc[2] + rc[3]);
    }
}

__global__ void zero_acc_kernel(double* acc) { acc[0] = 0.0; acc[1] = 0.0; }

__global__ void finalize_kernel(const double* acc, float* out) {
    out[0] = (acc[1] == 0.0) ? 0.0f : (float)(acc[0] / acc[1]);
}

// ---------------- launch -----------------------------------------------------

extern "C" void kernel_launch(void* const* d_in, const int* in_sizes, int n_in,
                              void* d_out, int out_size, void* d_ws, size_t ws_size,
                              hipStream_t stream) {
    const float* n_pred = (const float*)d_in[0];
    const float* src    = (const float*)d_in[1];

    const size_t vol_bytes = (size_t)2 * PVOL * sizeof(float4);  // 10,061,824
    const size_t need = vol_bytes + (size_t)NBLK2 * sizeof(float2);

    if (ws_size >= need) {
        float4* q = (float4*)d_ws;
        float2* partials = (float2*)((char*)d_ws + vol_bytes);
        int nblk = (2 * PVOL + 255) / 256;  // 2457
        pad_normalize_kernel<<<nblk, 256, 0, stream>>>(n_pred, src, q);
        dim3 grid(16, 32, 2);  // (y-tiles of 4, z-tiles of 2, batch) = 1024 blocks
        stencil_col2_kernel<<<grid, 256, 0, stream>>>(q, partials);
        reduce_kernel<<<1, 256, 0, stream>>>(partials, (float*)d_out);
    } else {
        double* acc = (double*)d_ws;
        zero_acc_kernel<<<1, 1, 0, stream>>>(acc);
        dim3 grid(8, 8, 16);
        repulsion_fused_kernel<<<grid, 256, 0, stream>>>(n_pred, src, acc);
        finalize_kernel<<<1, 1, 0, stream>>>(acc, (float*)d_out);
    }
}